// Round 1
// 1927.788 us; speedup vs baseline: 1.0902x; 1.0902x over previous
//
#include <hip/hip_runtime.h>
#include <hip/hip_bf16.h>

#define BATCH 32
#define KC 3
#define NP 512
#define FIN 64
#define FOUT 64
#define TP 64
#define COLS (FOUT*TP)   // 4096
#define KDIM (KC*NP)     // 1536

typedef unsigned short ushort_t;
typedef __attribute__((ext_vector_type(8))) short short8;
typedef __attribute__((ext_vector_type(4))) float f32x4;

__device__ __forceinline__ unsigned short f2bf(float f) {
    unsigned u = __float_as_uint(f);
    return (unsigned short)((u + 0x7FFF + ((u >> 16) & 1)) >> 16);
}
__device__ __forceinline__ float bf2f(unsigned short h) {
    return __uint_as_float(((unsigned)h) << 16);
}

#define GLDS16(g, l)                                                          \
    __builtin_amdgcn_global_load_lds(                                         \
        (const __attribute__((address_space(1))) void*)(g),                   \
        (__attribute__((address_space(3))) void*)(l), 16, 0, 0)

// ---------------------------------------------------------------------------
// K1: softmax -> A_eff, emitted as bf16 hi/lo pair. Layout [c][k][n][m].
// ---------------------------------------------------------------------------
__global__ __launch_bounds__(256) void k_softmax(
    const float* __restrict__ scores, const float* __restrict__ adj,
    const float* __restrict__ mask, const float* __restrict__ cheb,
    unsigned short* __restrict__ Ah, unsigned short* __restrict__ Al, int b0)
{
    const int n = blockIdx.x;
    const int k = blockIdx.y;
    const int c = blockIdx.z;
    const int b = b0 + c;
    const int tid = threadIdx.x;
    const size_t srow = (((size_t)b*KC + k)*NP + n)*NP;
    const size_t krow = ((size_t)k*NP + n)*NP;
    const size_t arow = (size_t)n*NP;

    float v0 = scores[srow+tid]     + adj[arow+tid]    *mask[krow+tid];
    float v1 = scores[srow+tid+256] + adj[arow+tid+256]*mask[krow+tid+256];

    float mx = fmaxf(v0, v1);
    #pragma unroll
    for (int off=32; off>0; off>>=1) mx = fmaxf(mx, __shfl_down(mx, off, 64));
    __shared__ float rmax[4], rsum[4];
    const int wv = tid>>6, ln = tid&63;
    if (ln==0) rmax[wv] = mx;
    __syncthreads();
    mx = fmaxf(fmaxf(rmax[0],rmax[1]), fmaxf(rmax[2],rmax[3]));

    const float e0 = __expf(v0-mx), e1 = __expf(v1-mx);
    float s = e0+e1;
    #pragma unroll
    for (int off=32; off>0; off>>=1) s += __shfl_down(s, off, 64);
    if (ln==0) rsum[wv] = s;
    __syncthreads();
    const float inv = 1.0f/(rsum[0]+rsum[1]+rsum[2]+rsum[3]);

    const size_t orow = (((size_t)c*KC + k)*NP + n)*NP;
    float a0 = cheb[krow+tid]    *e0*inv;
    float a1 = cheb[krow+tid+256]*e1*inv;
    unsigned short h0 = f2bf(a0), h1 = f2bf(a1);
    unsigned short l0 = f2bf(a0 - bf2f(h0)), l1 = f2bf(a1 - bf2f(h1));
    Ah[orow+tid]     = h0;  Al[orow+tid]     = l0;
    Ah[orow+tid+256] = h1;  Al[orow+tid+256] = l1;
}

// ---------------------------------------------------------------------------
// K2: W[c, k*512+m, o*64+t] = sum_i Theta[k,i,o] * x[b,m,i,t]  (fp32, unchanged)
// ---------------------------------------------------------------------------
#define WOS 65
__global__ __launch_bounds__(256) void k_W(
    const float* __restrict__ x, const float* __restrict__ Theta,
    float* __restrict__ W, int b0)
{
    __shared__ float sm[FIN*TP + KC*FOUT*WOS];
    float* Xm = sm;
    float* Th = sm + FIN*TP;
    float* Wo = sm + FIN*TP;   // alias, reused after compute

    const int m = blockIdx.x, c = blockIdx.y, b = b0 + c;
    const int tid = threadIdx.x;

    const float4* xg = (const float4*)(x + (((size_t)b*NP + m)*FIN)*TP);
    #pragma unroll
    for (int j=0;j<4;j++) ((float4*)Xm)[tid + j*256] = xg[tid + j*256];
    const float4* tg = (const float4*)Theta;
    #pragma unroll
    for (int j=0;j<12;j++) ((float4*)Th)[tid + j*256] = tg[tid + j*256];
    __syncthreads();

    const int o = tid & 63, tw = tid >> 6;
    float acc[KC][16];
    #pragma unroll
    for (int k=0;k<KC;k++)
        #pragma unroll
        for (int j=0;j<16;j++) acc[k][j]=0.f;

    for (int i=0;i<FIN;i++) {
        float4 xv[4];
        #pragma unroll
        for (int q=0;q<4;q++) xv[q] = *(const float4*)&Xm[i*TP + tw*16 + q*4];
        float th[KC];
        #pragma unroll
        for (int k=0;k<KC;k++) th[k] = Th[(k*FIN + i)*FOUT + o];
        #pragma unroll
        for (int k=0;k<KC;k++) {
            #pragma unroll
            for (int q=0;q<4;q++) {
                acc[k][q*4+0] += th[k]*xv[q].x;
                acc[k][q*4+1] += th[k]*xv[q].y;
                acc[k][q*4+2] += th[k]*xv[q].z;
                acc[k][q*4+3] += th[k]*xv[q].w;
            }
        }
    }
    __syncthreads();

    #pragma unroll
    for (int k=0;k<KC;k++)
        #pragma unroll
        for (int q=0;q<4;q++)
            *(float4*)&Wo[(k*FOUT + o)*WOS + tw*16 + q*4] =
                make_float4(acc[k][q*4],acc[k][q*4+1],acc[k][q*4+2],acc[k][q*4+3]);
    __syncthreads();

    float* Wc = W + ((size_t)c*KDIM)*COLS;
    #pragma unroll
    for (int j=0;j<12;j++) {
        int f4  = tid + j*256;
        int lin = f4*4;
        int k   = lin >> 12;
        float4 v = *(const float4*)&Wo[(k*FOUT + ((lin>>6)&63))*WOS + (lin&63)];
        *(float4*)&Wc[((size_t)(k*NP + m))*COLS + (lin & 4095)] = v;
    }
}

// ---------------------------------------------------------------------------
// K2b: transpose W[km][col] fp32 -> Wt[col][km] bf16 hi/lo. 64x64 tiles.
// ---------------------------------------------------------------------------
__global__ __launch_bounds__(256) void k_trans(
    const float* __restrict__ W,
    unsigned short* __restrict__ Wth, unsigned short* __restrict__ Wtl)
{
    __shared__ float Ls[64][68];
    const int km0 = blockIdx.x*64, col0 = blockIdx.y*64, c = blockIdx.z;
    const float* Wc = W + (size_t)c*KDIM*COLS;
    const int tid = threadIdx.x;
    const int r = tid >> 4, f4 = tid & 15;
    #pragma unroll
    for (int j=0;j<4;j++) {
        float4 v = *(const float4*)&Wc[(size_t)(km0 + r + j*16)*COLS + col0 + f4*4];
        *(float4*)&Ls[r + j*16][f4*4] = v;
    }
    __syncthreads();
    const int oc = tid >> 2, seg = tid & 3;   // output row (col), km segment of 16
    unsigned short h[16], l[16];
    #pragma unroll
    for (int u=0;u<16;u++) {
        float f = Ls[seg*16 + u][oc];
        h[u] = f2bf(f);
        l[u] = f2bf(f - bf2f(h[u]));
    }
    size_t off = ((size_t)c*COLS + col0 + oc)*KDIM + km0 + seg*16;
    *(uint4*)&Wth[off]   = *(const uint4*)&h[0];
    *(uint4*)&Wth[off+8] = *(const uint4*)&h[8];
    *(uint4*)&Wtl[off]   = *(const uint4*)&l[0];
    *(uint4*)&Wtl[off+8] = *(const uint4*)&l[8];
}

// ---------------------------------------------------------------------------
// K3: bf16x3 MFMA GEMM, FUSED single pass. out[b,n,col] = relu( sum A*W ),
// 128x128 tile, 4 waves 2x2, each wave 4x4 of 16x16x32 MFMAs.
// Per 32-wide K-chunk: stage Ah,Al,Wh,Wl -> 48 MFMAs (AhWh + AlWh + AhWl)
// between ONE barrier pair (was 3 passes x 16 MFMAs x 3 barrier pairs).
// LDS granule-XOR swizzle (slot ^= (row>>1)&3) applied via pre-swizzled
// GLOBAL source (global_load_lds dest must stay linear) + same XOR on the
// ds_read side: kills the 8-way bank conflict (64B rows -> 2 slots/128B
// window for 16 lanes). Read-side XOR is lane-constant -> no inner-loop VALU.
// ---------------------------------------------------------------------------
__global__ __launch_bounds__(256) void k_gemm(
    const unsigned short* __restrict__ Ah, const unsigned short* __restrict__ Al,
    const unsigned short* __restrict__ Wth, const unsigned short* __restrict__ Wtl,
    float* __restrict__ out, int b0)
{
    __shared__ __align__(16) unsigned short Ash[128*32];
    __shared__ __align__(16) unsigned short Asl[128*32];
    __shared__ __align__(16) unsigned short Bsh[128*32];
    __shared__ __align__(16) unsigned short Bsl[128*32];

    const int tid  = threadIdx.x;
    const int lane = tid & 63, wave = tid >> 6;
    const int wr = wave >> 1, wc = wave & 1;
    const int lr = lane & 15, quad = lane >> 4;
    const int n0 = blockIdx.x * 128, col0 = blockIdx.y * 128, c = blockIdx.z;

    const size_t cA = (size_t)c * KC*NP*NP;
    const size_t cW = (size_t)c * COLS*KDIM;
    const unsigned short* Ah_ = Ah  + cA;
    const unsigned short* Al_ = Al  + cA;
    const unsigned short* Bh_ = Wth + cW;
    const unsigned short* Bl_ = Wtl + cW;

    f32x4 acc[4][4];
    #pragma unroll
    for (int i=0;i<4;i++)
        #pragma unroll
        for (int j=0;j<4;j++)
            acc[i][j] = (f32x4){0.f,0.f,0.f,0.f};

    const int sr   = tid >> 2;                          // staging row 0..63
    // staged slot s holds global granule s ^ ((row>>1)&3); (tid>>3)&3 == (row>>1)&3
    const int qsw  = (((tid & 3) ^ ((tid >> 3) & 3)) * 8);

    unsigned short* lAh0 = Ash + tid*8;  unsigned short* lAh1 = Ash + 2048 + tid*8;
    unsigned short* lAl0 = Asl + tid*8;  unsigned short* lAl1 = Asl + 2048 + tid*8;
    unsigned short* lBh0 = Bsh + tid*8;  unsigned short* lBh1 = Bsh + 2048 + tid*8;
    unsigned short* lBl0 = Bsl + tid*8;  unsigned short* lBl1 = Bsl + 2048 + tid*8;

    // read-side swizzle: slot = quad ^ ((row>>1)&3); row>>1 & 3 == (lr>>1)&3
    const int rq = (quad ^ ((lr >> 1) & 3)) * 8;

    #pragma unroll 1
    for (int km0=0; km0<KDIM; km0+=32) {
        const int kk = km0 >> 9, m0 = km0 & (NP-1);
        const unsigned short* gah = Ah_ + ((size_t)(kk*NP + n0 + sr))*NP + m0 + qsw;
        const unsigned short* gal = Al_ + ((size_t)(kk*NP + n0 + sr))*NP + m0 + qsw;
        const unsigned short* gbh = Bh_ + ((size_t)(col0 + sr))*KDIM + km0 + qsw;
        const unsigned short* gbl = Bl_ + ((size_t)(col0 + sr))*KDIM + km0 + qsw;
        GLDS16(gah,           lAh0);
        GLDS16(gah + 64*NP,   lAh1);
        GLDS16(gal,           lAl0);
        GLDS16(gal + 64*NP,   lAl1);
        GLDS16(gbh,           lBh0);
        GLDS16(gbh + 64*KDIM, lBh1);
        GLDS16(gbl,           lBl0);
        GLDS16(gbl + 64*KDIM, lBl1);
        __syncthreads();

        short8 ah[4], al[4], bh[4], bl[4];
        #pragma unroll
        for (int i=0;i<4;i++) {
            const int ra = (wr*64 + i*16 + lr)*32 + rq;
            ah[i] = *(const short8*)&Ash[ra];
            al[i] = *(const short8*)&Asl[ra];
        }
        #pragma unroll
        for (int j=0;j<4;j++) {
            const int rb = (wc*64 + j*16 + lr)*32 + rq;
            bh[j] = *(const short8*)&Bsh[rb];
            bl[j] = *(const short8*)&Bsl[rb];
        }
        #pragma unroll
        for (int i=0;i<4;i++)
            #pragma unroll
            for (int j=0;j<4;j++) {
                acc[i][j] = __builtin_amdgcn_mfma_f32_16x16x32_bf16(
                    ah[i], bh[j], acc[i][j], 0, 0, 0);
                acc[i][j] = __builtin_amdgcn_mfma_f32_16x16x32_bf16(
                    al[i], bh[j], acc[i][j], 0, 0, 0);
                acc[i][j] = __builtin_amdgcn_mfma_f32_16x16x32_bf16(
                    ah[i], bl[j], acc[i][j], 0, 0, 0);
            }
        __syncthreads();
    }

    const size_t ob = ((size_t)(b0 + c)*NP + n0 + wr*64)*COLS + col0 + wc*64;
    #pragma unroll
    for (int i=0;i<4;i++) {
        #pragma unroll
        for (int r=0;r<4;r++) {
            const size_t row_off = ob + (size_t)(i*16 + quad*4 + r)*COLS;
            #pragma unroll
            for (int j=0;j<4;j++)
                out[row_off + j*16 + lr] = fmaxf(acc[i][j][r], 0.f);
        }
    }
}

// ---------------------------------------------------------------------------
extern "C" void kernel_launch(void* const* d_in, const int* in_sizes, int n_in,
                              void* d_out, int out_size, void* d_ws, size_t ws_size,
                              hipStream_t stream)
{
    const float* x      = (const float*)d_in[0];
    const float* scores = (const float*)d_in[1];
    const float* adj    = (const float*)d_in[2];
    const float* cheb   = (const float*)d_in[3];
    const float* Theta  = (const float*)d_in[4];
    const float* mask   = (const float*)d_in[5];
    float* out = (float*)d_out;

    // per-batch workspace bytes
    const size_t eA  = (size_t)KC*NP*NP;       // 786432 elems per A array
    const size_t eW  = (size_t)KDIM*COLS;      // 6291456 elems
    const size_t perB = 2*eA*2 + eW*4 + 2*eW*2;  // Ah+Al + W(fp32) + Wth+Wtl

    int C = (int)(ws_size / perB);
    if (C < 1) C = 1;
    if (C > BATCH) C = BATCH;
    while (BATCH % C) C--;

    char* p = (char*)d_ws;
    unsigned short* Ah  = (unsigned short*)p;  p += (size_t)C*eA*2;
    unsigned short* Al  = (unsigned short*)p;  p += (size_t)C*eA*2;
    unsigned short* Wth = (unsigned short*)p;  p += (size_t)C*eW*2;
    unsigned short* Wtl = (unsigned short*)p;  p += (size_t)C*eW*2;
    float*          W   = (float*)p;

    for (int b0 = 0; b0 < BATCH; b0 += C) {
        k_softmax<<<dim3(NP, KC, C), 256, 0, stream>>>(scores, adj, mask, cheb, Ah, Al, b0);
        k_W     <<<dim3(NP, C),      256, 0, stream>>>(x, Theta, W, b0);
        k_trans <<<dim3(KDIM/64, COLS/64, C), 256, 0, stream>>>(W, Wth, Wtl);
        k_gemm  <<<dim3(NP/128, COLS/128, C), 256, 0, stream>>>(Ah, Al, Wth, Wtl, out, b0);
    }
}

// Round 2
// 1812.699 us; speedup vs baseline: 1.1595x; 1.0635x over previous
//
#include <hip/hip_runtime.h>
#include <hip/hip_bf16.h>

#define BATCH 32
#define KC 3
#define NP 512
#define FIN 64
#define FOUT 64
#define TP 64
#define COLS (FOUT*TP)   // 4096
#define KDIM (KC*NP)     // 1536

typedef unsigned short ushort_t;
typedef __attribute__((ext_vector_type(8))) short short8;
typedef __attribute__((ext_vector_type(4))) float f32x4;

__device__ __forceinline__ unsigned short f2bf(float f) {
    unsigned u = __float_as_uint(f);
    return (unsigned short)((u + 0x7FFF + ((u >> 16) & 1)) >> 16);
}
__device__ __forceinline__ float bf2f(unsigned short h) {
    return __uint_as_float(((unsigned)h) << 16);
}

#define GLDS16(g, l)                                                          \
    __builtin_amdgcn_global_load_lds(                                         \
        (const __attribute__((address_space(1))) void*)(g),                   \
        (__attribute__((address_space(3))) void*)(l), 16, 0, 0)

// ---------------------------------------------------------------------------
// K1: softmax -> A_eff, emitted as bf16 hi/lo pair. Layout [c][k][n][m].
// ---------------------------------------------------------------------------
__global__ __launch_bounds__(256) void k_softmax(
    const float* __restrict__ scores, const float* __restrict__ adj,
    const float* __restrict__ mask, const float* __restrict__ cheb,
    unsigned short* __restrict__ Ah, unsigned short* __restrict__ Al, int b0)
{
    const int n = blockIdx.x;
    const int k = blockIdx.y;
    const int c = blockIdx.z;
    const int b = b0 + c;
    const int tid = threadIdx.x;
    const size_t srow = (((size_t)b*KC + k)*NP + n)*NP;
    const size_t krow = ((size_t)k*NP + n)*NP;
    const size_t arow = (size_t)n*NP;

    float v0 = scores[srow+tid]     + adj[arow+tid]    *mask[krow+tid];
    float v1 = scores[srow+tid+256] + adj[arow+tid+256]*mask[krow+tid+256];

    float mx = fmaxf(v0, v1);
    #pragma unroll
    for (int off=32; off>0; off>>=1) mx = fmaxf(mx, __shfl_down(mx, off, 64));
    __shared__ float rmax[4], rsum[4];
    const int wv = tid>>6, ln = tid&63;
    if (ln==0) rmax[wv] = mx;
    __syncthreads();
    mx = fmaxf(fmaxf(rmax[0],rmax[1]), fmaxf(rmax[2],rmax[3]));

    const float e0 = __expf(v0-mx), e1 = __expf(v1-mx);
    float s = e0+e1;
    #pragma unroll
    for (int off=32; off>0; off>>=1) s += __shfl_down(s, off, 64);
    if (ln==0) rsum[wv] = s;
    __syncthreads();
    const float inv = 1.0f/(rsum[0]+rsum[1]+rsum[2]+rsum[3]);

    const size_t orow = (((size_t)c*KC + k)*NP + n)*NP;
    float a0 = cheb[krow+tid]    *e0*inv;
    float a1 = cheb[krow+tid+256]*e1*inv;
    unsigned short h0 = f2bf(a0), h1 = f2bf(a1);
    unsigned short l0 = f2bf(a0 - bf2f(h0)), l1 = f2bf(a1 - bf2f(h1));
    Ah[orow+tid]     = h0;  Al[orow+tid]     = l0;
    Ah[orow+tid+256] = h1;  Al[orow+tid+256] = l1;
}

// ---------------------------------------------------------------------------
// K2: Wh/Wl[c, k*512+m, o*64+t] = bf16 hi/lo of sum_i Theta[k,i,o]*x[b,m,i,t]
// fp32 compute in registers; hi/lo split in the epilogue (no fp32 round-trip).
// ---------------------------------------------------------------------------
#define WOS 65
__global__ __launch_bounds__(256) void k_W(
    const float* __restrict__ x, const float* __restrict__ Theta,
    unsigned short* __restrict__ Wh, unsigned short* __restrict__ Wl, int b0)
{
    __shared__ float sm[FIN*TP + KC*FOUT*WOS];
    float* Xm = sm;
    float* Th = sm + FIN*TP;
    float* Wo = sm + FIN*TP;   // alias, reused after compute

    const int m = blockIdx.x, c = blockIdx.y, b = b0 + c;
    const int tid = threadIdx.x;

    const float4* xg = (const float4*)(x + (((size_t)b*NP + m)*FIN)*TP);
    #pragma unroll
    for (int j=0;j<4;j++) ((float4*)Xm)[tid + j*256] = xg[tid + j*256];
    const float4* tg = (const float4*)Theta;
    #pragma unroll
    for (int j=0;j<12;j++) ((float4*)Th)[tid + j*256] = tg[tid + j*256];
    __syncthreads();

    const int o = tid & 63, tw = tid >> 6;
    float acc[KC][16];
    #pragma unroll
    for (int k=0;k<KC;k++)
        #pragma unroll
        for (int j=0;j<16;j++) acc[k][j]=0.f;

    for (int i=0;i<FIN;i++) {
        float4 xv[4];
        #pragma unroll
        for (int q=0;q<4;q++) xv[q] = *(const float4*)&Xm[i*TP + tw*16 + q*4];
        float th[KC];
        #pragma unroll
        for (int k=0;k<KC;k++) th[k] = Th[(k*FIN + i)*FOUT + o];
        #pragma unroll
        for (int k=0;k<KC;k++) {
            #pragma unroll
            for (int q=0;q<4;q++) {
                acc[k][q*4+0] += th[k]*xv[q].x;
                acc[k][q*4+1] += th[k]*xv[q].y;
                acc[k][q*4+2] += th[k]*xv[q].z;
                acc[k][q*4+3] += th[k]*xv[q].w;
            }
        }
    }
    __syncthreads();

    #pragma unroll
    for (int k=0;k<KC;k++)
        #pragma unroll
        for (int q=0;q<4;q++)
            *(float4*)&Wo[(k*FOUT + o)*WOS + tw*16 + q*4] =
                make_float4(acc[k][q*4],acc[k][q*4+1],acc[k][q*4+2],acc[k][q*4+3]);
    __syncthreads();

    unsigned short* Whc = Wh + ((size_t)c*KDIM)*COLS;
    unsigned short* Wlc = Wl + ((size_t)c*KDIM)*COLS;
    #pragma unroll
    for (int j=0;j<6;j++) {
        int lin8 = (tid + j*256)*8;
        int k    = lin8 >> 12;
        int idx  = lin8 & 4095;
        const float* src = &Wo[(k*FOUT + (idx>>6))*WOS + (idx & 63)];
        unsigned short h8[8], l8[8];
        #pragma unroll
        for (int u=0;u<8;u++) {
            float f = src[u];
            h8[u] = f2bf(f);
            l8[u] = f2bf(f - bf2f(h8[u]));
        }
        size_t off = ((size_t)(k*NP + m))*COLS + idx;
        *(uint4*)&Whc[off] = *(const uint4*)h8;
        *(uint4*)&Wlc[off] = *(const uint4*)l8;
    }
}

// ---------------------------------------------------------------------------
// K2b: transpose Wh/Wl [km][col] bf16 -> Wth/Wtl [col][km] bf16. 64x64 tiles.
// Pure data movement now (hi/lo split already done in k_W).
// ---------------------------------------------------------------------------
__global__ __launch_bounds__(256) void k_trans(
    const unsigned short* __restrict__ Wh, const unsigned short* __restrict__ Wl,
    unsigned short* __restrict__ Wth, unsigned short* __restrict__ Wtl)
{
    __shared__ unsigned short Lh[64][72];
    __shared__ unsigned short Ll[64][72];
    const int km0 = blockIdx.x*64, col0 = blockIdx.y*64, c = blockIdx.z;
    const unsigned short* Whc = Wh + (size_t)c*KDIM*COLS;
    const unsigned short* Wlc = Wl + (size_t)c*KDIM*COLS;
    const int tid = threadIdx.x;
    #pragma unroll
    for (int p=0;p<2;p++) {
        int lin = tid*8 + p*2048;
        int r = lin >> 6, o8 = lin & 63;
        *(uint4*)&Lh[r][o8] = *(const uint4*)&Whc[(size_t)(km0 + r)*COLS + col0 + o8];
        *(uint4*)&Ll[r][o8] = *(const uint4*)&Wlc[(size_t)(km0 + r)*COLS + col0 + o8];
    }
    __syncthreads();
    const int oc = tid >> 2, seg = tid & 3;   // output row (col), km segment of 16
    unsigned short h[16], l[16];
    #pragma unroll
    for (int u=0;u<16;u++) {
        h[u] = Lh[seg*16 + u][oc];
        l[u] = Ll[seg*16 + u][oc];
    }
    size_t off = ((size_t)c*COLS + col0 + oc)*KDIM + km0 + seg*16;
    *(uint4*)&Wth[off]   = *(const uint4*)&h[0];
    *(uint4*)&Wth[off+8] = *(const uint4*)&h[8];
    *(uint4*)&Wtl[off]   = *(const uint4*)&l[0];
    *(uint4*)&Wtl[off+8] = *(const uint4*)&l[8];
}

// ---------------------------------------------------------------------------
// K3: bf16x3 fused MFMA GEMM, double-buffered LDS (2x32KB) + XCD swizzle.
// Per 32-wide K-chunk: ONE __syncthreads (drains prev stage), then issue next
// chunk's global_load_lds (lands under compute), ds_read + 48 MFMAs.
// XCD swizzle: flat%8 -> one contiguous c-slice per XCD (A slice 3.1MB fits
// per-XCD L2; the 4 n-blocks sharing each B panel run adjacently).
// LDS granule-XOR swizzle (slot ^= (row>>1)&3) via pre-swizzled global source.
// ---------------------------------------------------------------------------
__global__ __launch_bounds__(256) void k_gemm(
    const unsigned short* __restrict__ Ah, const unsigned short* __restrict__ Al,
    const unsigned short* __restrict__ Wth, const unsigned short* __restrict__ Wtl,
    float* __restrict__ out, int b0)
{
    __shared__ __align__(16) unsigned short Ash[2][128*32];
    __shared__ __align__(16) unsigned short Asl[2][128*32];
    __shared__ __align__(16) unsigned short Bsh[2][128*32];
    __shared__ __align__(16) unsigned short Bsl[2][128*32];

    const int tid  = threadIdx.x;
    const int lane = tid & 63, wave = tid >> 6;
    const int wr = wave >> 1, wc = wave & 1;
    const int lr = lane & 15, quad = lane >> 4;

    // XCD-aware bijective swizzle: nwg = 128*C is always divisible by 8.
    const int nwg  = gridDim.x * gridDim.y * gridDim.z;
    const int flat = blockIdx.x + gridDim.x * (blockIdx.y + gridDim.y * blockIdx.z);
    const int cpx  = nwg >> 3;
    const int swz  = (flat & 7) * cpx + (flat >> 3);
    const int n0   = (swz & 3) * 128;
    const int col0 = ((swz >> 2) & 31) * 128;
    const int c    = swz >> 7;

    const size_t cA = (size_t)c * KC*NP*NP;
    const size_t cW = (size_t)c * COLS*KDIM;
    const unsigned short* Ah_ = Ah  + cA;
    const unsigned short* Al_ = Al  + cA;
    const unsigned short* Bh_ = Wth + cW;
    const unsigned short* Bl_ = Wtl + cW;

    f32x4 acc[4][4];
    #pragma unroll
    for (int i=0;i<4;i++)
        #pragma unroll
        for (int j=0;j<4;j++)
            acc[i][j] = (f32x4){0.f,0.f,0.f,0.f};

    const int sr  = tid >> 2;                           // staging row 0..63
    // staged slot s holds global granule s ^ ((row>>1)&3); (tid>>3)&3 == (row>>1)&3
    const int qsw = (((tid & 3) ^ ((tid >> 3) & 3)) * 8);

    // read-side swizzle: slot = quad ^ ((row>>1)&3); (row>>1)&3 == (lr>>1)&3
    const int rq = (quad ^ ((lr >> 1) & 3)) * 8;

    auto STAGE = [&](int bb, int km0) {
        const int kk = km0 >> 9, m0 = km0 & (NP-1);
        const unsigned short* gah = Ah_ + ((size_t)(kk*NP + n0 + sr))*NP + m0 + qsw;
        const unsigned short* gal = Al_ + ((size_t)(kk*NP + n0 + sr))*NP + m0 + qsw;
        const unsigned short* gbh = Bh_ + ((size_t)(col0 + sr))*KDIM + km0 + qsw;
        const unsigned short* gbl = Bl_ + ((size_t)(col0 + sr))*KDIM + km0 + qsw;
        GLDS16(gah,           &Ash[bb][tid*8]);
        GLDS16(gah + 64*NP,   &Ash[bb][2048 + tid*8]);
        GLDS16(gal,           &Asl[bb][tid*8]);
        GLDS16(gal + 64*NP,   &Asl[bb][2048 + tid*8]);
        GLDS16(gbh,           &Bsh[bb][tid*8]);
        GLDS16(gbh + 64*KDIM, &Bsh[bb][2048 + tid*8]);
        GLDS16(gbl,           &Bsl[bb][tid*8]);
        GLDS16(gbl + 64*KDIM, &Bsl[bb][2048 + tid*8]);
    };

    STAGE(0, 0);
    int bb = 0;

    #pragma unroll 1
    for (int t = 0; t < KDIM/32; ++t) {
        __syncthreads();                       // buf bb ready; prev reads done
        if (t+1 < KDIM/32) STAGE(bb^1, 32*(t+1));   // lands under compute

        short8 ah[4], al[4], bh[4], bl[4];
        #pragma unroll
        for (int i=0;i<4;i++) {
            const int ra = (wr*64 + i*16 + lr)*32 + rq;
            ah[i] = *(const short8*)&Ash[bb][ra];
            al[i] = *(const short8*)&Asl[bb][ra];
        }
        #pragma unroll
        for (int j=0;j<4;j++) {
            const int rb = (wc*64 + j*16 + lr)*32 + rq;
            bh[j] = *(const short8*)&Bsh[bb][rb];
            bl[j] = *(const short8*)&Bsl[bb][rb];
        }
        #pragma unroll
        for (int i=0;i<4;i++)
            #pragma unroll
            for (int j=0;j<4;j++) {
                acc[i][j] = __builtin_amdgcn_mfma_f32_16x16x32_bf16(
                    ah[i], bh[j], acc[i][j], 0, 0, 0);
                acc[i][j] = __builtin_amdgcn_mfma_f32_16x16x32_bf16(
                    al[i], bh[j], acc[i][j], 0, 0, 0);
                acc[i][j] = __builtin_amdgcn_mfma_f32_16x16x32_bf16(
                    ah[i], bl[j], acc[i][j], 0, 0, 0);
            }
        bb ^= 1;
    }

    const size_t ob = ((size_t)(b0 + c)*NP + n0 + wr*64)*COLS + col0 + wc*64;
    #pragma unroll
    for (int i=0;i<4;i++) {
        #pragma unroll
        for (int r=0;r<4;r++) {
            const size_t row_off = ob + (size_t)(i*16 + quad*4 + r)*COLS;
            #pragma unroll
            for (int j=0;j<4;j++)
                out[row_off + j*16 + lr] = fmaxf(acc[i][j][r], 0.f);
        }
    }
}

// ---------------------------------------------------------------------------
extern "C" void kernel_launch(void* const* d_in, const int* in_sizes, int n_in,
                              void* d_out, int out_size, void* d_ws, size_t ws_size,
                              hipStream_t stream)
{
    const float* x      = (const float*)d_in[0];
    const float* scores = (const float*)d_in[1];
    const float* adj    = (const float*)d_in[2];
    const float* cheb   = (const float*)d_in[3];
    const float* Theta  = (const float*)d_in[4];
    const float* mask   = (const float*)d_in[5];
    float* out = (float*)d_out;

    // per-batch workspace bytes (same footprint as before: fp32 W slot now
    // holds the untransposed bf16 hi/lo pair)
    const size_t eA  = (size_t)KC*NP*NP;       // 786432 elems per A array
    const size_t eW  = (size_t)KDIM*COLS;      // 6291456 elems
    const size_t perB = 2*eA*2 + 4*eW*2;       // Ah+Al + (Wh,Wl,Wth,Wtl)

    int C = (int)(ws_size / perB);
    if (C < 1) C = 1;
    if (C > BATCH) C = BATCH;
    while (BATCH % C) C--;

    char* p = (char*)d_ws;
    unsigned short* Ah  = (unsigned short*)p;  p += (size_t)C*eA*2;
    unsigned short* Al  = (unsigned short*)p;  p += (size_t)C*eA*2;
    unsigned short* Wth = (unsigned short*)p;  p += (size_t)C*eW*2;
    unsigned short* Wtl = (unsigned short*)p;  p += (size_t)C*eW*2;
    unsigned short* Wh  = (unsigned short*)p;  p += (size_t)C*eW*2;
    unsigned short* Wl  = (unsigned short*)p;

    for (int b0 = 0; b0 < BATCH; b0 += C) {
        k_softmax<<<dim3(NP, KC, C), 256, 0, stream>>>(scores, adj, mask, cheb, Ah, Al, b0);
        k_W     <<<dim3(NP, C),      256, 0, stream>>>(x, Theta, Wh, Wl, b0);
        k_trans <<<dim3(KDIM/64, COLS/64, C), 256, 0, stream>>>(Wh, Wl, Wth, Wtl);
        k_gemm  <<<dim3(NP/128, COLS/128, C), 256, 0, stream>>>(Ah, Al, Wth, Wtl, out, b0);
    }
}

// Round 3
// 1642.370 us; speedup vs baseline: 1.2797x; 1.1037x over previous
//
#include <hip/hip_runtime.h>
#include <hip/hip_bf16.h>

#define BATCH 32
#define KC 3
#define NP 512
#define FIN 64
#define FOUT 64
#define TP 64
#define COLS (FOUT*TP)   // 4096  (also = FIN*TP = x columns (i,t))
#define KDIM (KC*NP)     // 1536

typedef unsigned short ushort_t;
typedef __attribute__((ext_vector_type(8))) short short8;
typedef __attribute__((ext_vector_type(4))) float f32x4;

__device__ __forceinline__ unsigned short f2bf(float f) {
    unsigned u = __float_as_uint(f);
    return (unsigned short)((u + 0x7FFF + ((u >> 16) & 1)) >> 16);
}
__device__ __forceinline__ float bf2f(unsigned short h) {
    return __uint_as_float(((unsigned)h) << 16);
}

#define GLDS16(g, l)                                                          \
    __builtin_amdgcn_global_load_lds(                                         \
        (const __attribute__((address_space(1))) void*)(g),                   \
        (__attribute__((address_space(3))) void*)(l), 16, 0, 0)

// ---------------------------------------------------------------------------
// K1: softmax -> A_eff, emitted as bf16 hi/lo pair. Layout [c][k][n][m].
// ---------------------------------------------------------------------------
__global__ __launch_bounds__(256) void k_softmax(
    const float* __restrict__ scores, const float* __restrict__ adj,
    const float* __restrict__ mask, const float* __restrict__ cheb,
    unsigned short* __restrict__ Ah, unsigned short* __restrict__ Al, int b0)
{
    const int n = blockIdx.x;
    const int k = blockIdx.y;
    const int c = blockIdx.z;
    const int b = b0 + c;
    const int tid = threadIdx.x;
    const size_t srow = (((size_t)b*KC + k)*NP + n)*NP;
    const size_t krow = ((size_t)k*NP + n)*NP;
    const size_t arow = (size_t)n*NP;

    float v0 = scores[srow+tid]     + adj[arow+tid]    *mask[krow+tid];
    float v1 = scores[srow+tid+256] + adj[arow+tid+256]*mask[krow+tid+256];

    float mx = fmaxf(v0, v1);
    #pragma unroll
    for (int off=32; off>0; off>>=1) mx = fmaxf(mx, __shfl_down(mx, off, 64));
    __shared__ float rmax[4], rsum[4];
    const int wv = tid>>6, ln = tid&63;
    if (ln==0) rmax[wv] = mx;
    __syncthreads();
    mx = fmaxf(fmaxf(rmax[0],rmax[1]), fmaxf(rmax[2],rmax[3]));

    const float e0 = __expf(v0-mx), e1 = __expf(v1-mx);
    float s = e0+e1;
    #pragma unroll
    for (int off=32; off>0; off>>=1) s += __shfl_down(s, off, 64);
    if (ln==0) rsum[wv] = s;
    __syncthreads();
    const float inv = 1.0f/(rsum[0]+rsum[1]+rsum[2]+rsum[3]);

    const size_t orow = (((size_t)c*KC + k)*NP + n)*NP;
    float a0 = cheb[krow+tid]    *e0*inv;
    float a1 = cheb[krow+tid+256]*e1*inv;
    unsigned short h0 = f2bf(a0), h1 = f2bf(a1);
    unsigned short l0 = f2bf(a0 - bf2f(h0)), l1 = f2bf(a1 - bf2f(h1));
    Ah[orow+tid]     = h0;  Al[orow+tid]     = l0;
    Ah[orow+tid+256] = h1;  Al[orow+tid+256] = l1;
}

// ---------------------------------------------------------------------------
// K2: transpose x [b][m][col] fp32 -> Xt[c][col][m] bf16 hi/lo (col = i*64+t).
// 64x64 tiles via LDS. Replaces the old k_W + k_trans W-building entirely.
// ---------------------------------------------------------------------------
__global__ __launch_bounds__(256) void k_xt(
    const float* __restrict__ x,
    unsigned short* __restrict__ Xth, unsigned short* __restrict__ Xtl, int b0)
{
    __shared__ float Ls[64][68];
    const int m0 = blockIdx.x*64, col0 = blockIdx.y*64, c = blockIdx.z;
    const int b = b0 + c;
    const float* xb = x + (size_t)b*NP*COLS;
    const int tid = threadIdx.x;
    const int r = tid >> 4, f4 = tid & 15;
    #pragma unroll
    for (int j=0;j<4;j++) {
        float4 v = *(const float4*)&xb[(size_t)(m0 + r + j*16)*COLS + col0 + f4*4];
        *(float4*)&Ls[r + j*16][f4*4] = v;
    }
    __syncthreads();
    const int oc = tid >> 2, seg = tid & 3;   // output row (col), m-segment of 16
    unsigned short h[16], l[16];
    #pragma unroll
    for (int u=0;u<16;u++) {
        float f = Ls[seg*16 + u][oc];
        h[u] = f2bf(f);
        l[u] = f2bf(f - bf2f(h[u]));
    }
    size_t off = ((size_t)c*COLS + col0 + oc)*NP + m0 + seg*16;
    *(uint4*)&Xth[off]   = *(const uint4*)&h[0];
    *(uint4*)&Xth[off+8] = *(const uint4*)&h[8];
    *(uint4*)&Xtl[off]   = *(const uint4*)&l[0];
    *(uint4*)&Xtl[off+8] = *(const uint4*)&l[8];
}

// ---------------------------------------------------------------------------
// K3: bf16x3 fused MFMA GEMM: Y[c,k,n,col] = sum_m A_k[n,m] * X[m,col].
// K = 512 (m). B-matrix = Xt (8.4 MB h+l per batch) -> L2-resident per XCD.
// Double-buffered LDS, one barrier/chunk, LDS granule-XOR swizzle via
// pre-swizzled global source. Block order per XCD slice: colg -> (k,n) -> colsub
// so A panels (3MB) + 4 B panels (1MB) stay L2-hot.
// Output Y is fp32, no relu (Theta applied exactly in k_theta).
// ---------------------------------------------------------------------------
__global__ __launch_bounds__(256) void k_gemm(
    const unsigned short* __restrict__ Ah, const unsigned short* __restrict__ Al,
    const unsigned short* __restrict__ Xth, const unsigned short* __restrict__ Xtl,
    float* __restrict__ Y)
{
    __shared__ __align__(16) unsigned short Ash[2][128*32];
    __shared__ __align__(16) unsigned short Asl[2][128*32];
    __shared__ __align__(16) unsigned short Bsh[2][128*32];
    __shared__ __align__(16) unsigned short Bsl[2][128*32];

    const int tid  = threadIdx.x;
    const int lane = tid & 63, wave = tid >> 6;
    const int wr = wave >> 1, wc = wave & 1;
    const int lr = lane & 15, quad = lane >> 4;

    // grid = dim3(384, C). flat dispatch id; c = flat % C (== XCD id when C=8,
    // so each XCD owns one contiguous batch slice). Within slice:
    // colg(8) -> kn(12: k*?,n) -> colsub(4): A panels reused across colg,
    // B panels reused by the 12 (k,n) blocks.
    const int Cg   = gridDim.y;
    const int flat = blockIdx.x + 384 * blockIdx.y;
    const int c    = flat % Cg;
    const int rr   = flat / Cg;          // 0..383
    const int colg = rr / 48;
    const int rem  = rr % 48;
    const int kn   = rem >> 2;           // 0..11
    const int colb = colg*4 + (rem & 3);
    const int k    = kn % 3;
    const int nb   = kn / 3;
    const int n0   = nb * 128, col0 = colb * 128;

    const unsigned short* Ah_ = Ah  + ((size_t)(c*KC + k)*NP)*NP;
    const unsigned short* Al_ = Al  + ((size_t)(c*KC + k)*NP)*NP;
    const unsigned short* Bh_ = Xth + (size_t)c*COLS*NP;
    const unsigned short* Bl_ = Xtl + (size_t)c*COLS*NP;

    f32x4 acc[4][4];
    #pragma unroll
    for (int i=0;i<4;i++)
        #pragma unroll
        for (int j=0;j<4;j++)
            acc[i][j] = (f32x4){0.f,0.f,0.f,0.f};

    const int sr  = tid >> 2;                           // staging row 0..63
    // staged slot s holds global granule s ^ ((row>>1)&3); (tid>>3)&3 == (row>>1)&3
    const int qsw = (((tid & 3) ^ ((tid >> 3) & 3)) * 8);
    // read-side swizzle: slot = quad ^ ((row>>1)&3); (row>>1)&3 == (lr>>1)&3
    const int rq  = (quad ^ ((lr >> 1) & 3)) * 8;

    auto STAGE = [&](int bb, int m0) {
        const unsigned short* gah = Ah_ + ((size_t)(n0 + sr))*NP + m0 + qsw;
        const unsigned short* gal = Al_ + ((size_t)(n0 + sr))*NP + m0 + qsw;
        const unsigned short* gbh = Bh_ + ((size_t)(col0 + sr))*NP + m0 + qsw;
        const unsigned short* gbl = Bl_ + ((size_t)(col0 + sr))*NP + m0 + qsw;
        GLDS16(gah,          &Ash[bb][tid*8]);
        GLDS16(gah + 64*NP,  &Ash[bb][2048 + tid*8]);
        GLDS16(gal,          &Asl[bb][tid*8]);
        GLDS16(gal + 64*NP,  &Asl[bb][2048 + tid*8]);
        GLDS16(gbh,          &Bsh[bb][tid*8]);
        GLDS16(gbh + 64*NP,  &Bsh[bb][2048 + tid*8]);
        GLDS16(gbl,          &Bsl[bb][tid*8]);
        GLDS16(gbl + 64*NP,  &Bsl[bb][2048 + tid*8]);
    };

    STAGE(0, 0);
    int bb = 0;

    #pragma unroll 1
    for (int t = 0; t < NP/32; ++t) {
        __syncthreads();                            // buf bb ready; prev reads done
        if (t+1 < NP/32) STAGE(bb^1, 32*(t+1));     // lands under compute

        short8 ah[4], al[4], bh[4], bl[4];
        #pragma unroll
        for (int i=0;i<4;i++) {
            const int ra = (wr*64 + i*16 + lr)*32 + rq;
            ah[i] = *(const short8*)&Ash[bb][ra];
            al[i] = *(const short8*)&Asl[bb][ra];
        }
        #pragma unroll
        for (int j=0;j<4;j++) {
            const int rb = (wc*64 + j*16 + lr)*32 + rq;
            bh[j] = *(const short8*)&Bsh[bb][rb];
            bl[j] = *(const short8*)&Bsl[bb][rb];
        }
        #pragma unroll
        for (int i=0;i<4;i++)
            #pragma unroll
            for (int j=0;j<4;j++) {
                acc[i][j] = __builtin_amdgcn_mfma_f32_16x16x32_bf16(
                    ah[i], bh[j], acc[i][j], 0, 0, 0);
                acc[i][j] = __builtin_amdgcn_mfma_f32_16x16x32_bf16(
                    al[i], bh[j], acc[i][j], 0, 0, 0);
                acc[i][j] = __builtin_amdgcn_mfma_f32_16x16x32_bf16(
                    ah[i], bl[j], acc[i][j], 0, 0, 0);
            }
        bb ^= 1;
    }

    float* Yc = Y + ((size_t)(c*KC + k)*NP + n0 + wr*64)*COLS + col0 + wc*64;
    #pragma unroll
    for (int i=0;i<4;i++) {
        #pragma unroll
        for (int r=0;r<4;r++) {
            const size_t row_off = (size_t)(i*16 + quad*4 + r)*COLS;
            #pragma unroll
            for (int j=0;j<4;j++)
                Yc[row_off + j*16 + lr] = acc[i][j][r];
        }
    }
}

// ---------------------------------------------------------------------------
// K4: out[b,n,o,t] = relu( sum_{k,i} Y[c,k,n,i*64+t] * Theta[k,i,o] ).
// fp32 VALU: per block (n,c): Ys rows staged to LDS (48KB), Theta from L2
// (coalesced 256B/wave per ki), thread = (o, 16 t's). 2.6e10 FLOP total.
// ---------------------------------------------------------------------------
__global__ __launch_bounds__(256) void k_theta(
    const float* __restrict__ Y, const float* __restrict__ Theta,
    float* __restrict__ out, int b0)
{
    __shared__ __align__(16) float Ys[KC*FIN*TP];   // 12288 floats, 48 KB
    const int n = blockIdx.x, c = blockIdx.y;
    const int tid = threadIdx.x;

    #pragma unroll
    for (int j=0;j<12;j++) {
        int f4  = tid + j*256;        // 0..3071
        int lin = f4*4;               // 0..12287
        int kk  = lin >> 12;          // /4096
        int off = lin & 4095;
        ((float4*)Ys)[f4] =
            *(const float4*)&Y[((size_t)(c*KC + kk)*NP + n)*COLS + off];
    }
    __syncthreads();

    const int o = tid & 63, tw = tid >> 6;
    float4 a0 = {0,0,0,0}, a1 = a0, a2 = a0, a3 = a0;

    #pragma unroll 8
    for (int ki = 0; ki < KC*FIN; ++ki) {
        float th = Theta[ki*FOUT + o];
        const float* ys = &Ys[ki*TP + tw*16];
        float4 y0 = *(const float4*)&ys[0];
        float4 y1 = *(const float4*)&ys[4];
        float4 y2 = *(const float4*)&ys[8];
        float4 y3 = *(const float4*)&ys[12];
        a0.x += th*y0.x; a0.y += th*y0.y; a0.z += th*y0.z; a0.w += th*y0.w;
        a1.x += th*y1.x; a1.y += th*y1.y; a1.z += th*y1.z; a1.w += th*y1.w;
        a2.x += th*y2.x; a2.y += th*y2.y; a2.z += th*y2.z; a2.w += th*y2.w;
        a3.x += th*y3.x; a3.y += th*y3.y; a3.z += th*y3.z; a3.w += th*y3.w;
    }

    float* og = out + (((size_t)(b0 + c)*NP + n)*FOUT + o)*TP + tw*16;
    float4 r0 = make_float4(fmaxf(a0.x,0.f), fmaxf(a0.y,0.f), fmaxf(a0.z,0.f), fmaxf(a0.w,0.f));
    float4 r1 = make_float4(fmaxf(a1.x,0.f), fmaxf(a1.y,0.f), fmaxf(a1.z,0.f), fmaxf(a1.w,0.f));
    float4 r2 = make_float4(fmaxf(a2.x,0.f), fmaxf(a2.y,0.f), fmaxf(a2.z,0.f), fmaxf(a2.w,0.f));
    float4 r3 = make_float4(fmaxf(a3.x,0.f), fmaxf(a3.y,0.f), fmaxf(a3.z,0.f), fmaxf(a3.w,0.f));
    *(float4*)&og[0]  = r0;
    *(float4*)&og[4]  = r1;
    *(float4*)&og[8]  = r2;
    *(float4*)&og[12] = r3;
}

// ---------------------------------------------------------------------------
extern "C" void kernel_launch(void* const* d_in, const int* in_sizes, int n_in,
                              void* d_out, int out_size, void* d_ws, size_t ws_size,
                              hipStream_t stream)
{
    const float* x      = (const float*)d_in[0];
    const float* scores = (const float*)d_in[1];
    const float* adj    = (const float*)d_in[2];
    const float* cheb   = (const float*)d_in[3];
    const float* Theta  = (const float*)d_in[4];
    const float* mask   = (const float*)d_in[5];
    float* out = (float*)d_out;

    const size_t eA = (size_t)KC*NP*NP;     // 786432 elems per A array
    const size_t eX = (size_t)COLS*NP;      // 2097152 elems per Xt array
    const size_t eY = (size_t)KC*NP*COLS;   // 6291456 fp32 elems
    const size_t perB = 2*eA*2 + 2*eX*2 + eY*4;   // ~36.7 MB per batch

    int C = (int)(ws_size / perB);
    if (C < 1) C = 1;
    if (C > 8) C = 8;            // one batch per XCD; keep L2 slices tight
    while (BATCH % C) C--;

    char* p = (char*)d_ws;
    unsigned short* Ah  = (unsigned short*)p;  p += (size_t)C*eA*2;
    unsigned short* Al  = (unsigned short*)p;  p += (size_t)C*eA*2;
    unsigned short* Xth = (unsigned short*)p;  p += (size_t)C*eX*2;
    unsigned short* Xtl = (unsigned short*)p;  p += (size_t)C*eX*2;
    float*          Yw  = (float*)p;

    for (int b0 = 0; b0 < BATCH; b0 += C) {
        k_softmax<<<dim3(NP, KC, C),  256, 0, stream>>>(scores, adj, mask, cheb, Ah, Al, b0);
        k_xt     <<<dim3(NP/64, COLS/64, C), 256, 0, stream>>>(x, Xth, Xtl, b0);
        k_gemm   <<<dim3(384, C),     256, 0, stream>>>(Ah, Al, Xth, Xtl, Yw);
        k_theta  <<<dim3(NP, C),      256, 0, stream>>>(Yw, Theta, out, b0);
    }
}

// Round 4
// 1315.085 us; speedup vs baseline: 1.5982x; 1.2489x over previous
//
#include <hip/hip_runtime.h>
#include <hip/hip_bf16.h>

#define BATCH 32
#define KC 3
#define NP 512
#define FIN 64
#define FOUT 64
#define TP 64
#define COLS (FOUT*TP)   // 4096  (also = FIN*TP = x columns (i,t))
#define KDIM (KC*NP)     // 1536

typedef unsigned short ushort_t;
typedef __attribute__((ext_vector_type(8))) short short8;
typedef __attribute__((ext_vector_type(4))) float f32x4;

__device__ __forceinline__ unsigned short f2bf(float f) {
    unsigned u = __float_as_uint(f);
    return (unsigned short)((u + 0x7FFF + ((u >> 16) & 1)) >> 16);
}
__device__ __forceinline__ float bf2f(unsigned short h) {
    return __uint_as_float(((unsigned)h) << 16);
}

#define GLDS16(g, l)                                                          \
    __builtin_amdgcn_global_load_lds(                                         \
        (const __attribute__((address_space(1))) void*)(g),                   \
        (__attribute__((address_space(3))) void*)(l), 16, 0, 0)

// ---------------------------------------------------------------------------
// K1 (fused): blocks [0, KC*NP): softmax -> A_eff bf16 hi/lo, [c][k][n][m].
//             blocks [KC*NP, KC*NP+512): transpose x -> Xt bf16 (hi only,
//             RNE; the dropped h_A*l_X term costs ~3e-5 absmax).
// ---------------------------------------------------------------------------
__global__ __launch_bounds__(256) void k_prep(
    const float* __restrict__ scores, const float* __restrict__ adj,
    const float* __restrict__ mask, const float* __restrict__ cheb,
    const float* __restrict__ x,
    unsigned short* __restrict__ Ah, unsigned short* __restrict__ Al,
    unsigned short* __restrict__ Xth, int b0)
{
    __shared__ float Ls[64][68];
    __shared__ float rmax[4], rsum[4];
    const int c = blockIdx.y;
    const int b = b0 + c;
    const int tid = threadIdx.x;

    if (blockIdx.x < KC*NP) {
        // ---- softmax path ----
        const int n = blockIdx.x & (NP-1);
        const int k = blockIdx.x >> 9;
        const size_t srow = (((size_t)b*KC + k)*NP + n)*NP;
        const size_t krow = ((size_t)k*NP + n)*NP;
        const size_t arow = (size_t)n*NP;

        float v0 = scores[srow+tid]     + adj[arow+tid]    *mask[krow+tid];
        float v1 = scores[srow+tid+256] + adj[arow+tid+256]*mask[krow+tid+256];

        float mx = fmaxf(v0, v1);
        #pragma unroll
        for (int off=32; off>0; off>>=1) mx = fmaxf(mx, __shfl_down(mx, off, 64));
        const int wv = tid>>6, ln = tid&63;
        if (ln==0) rmax[wv] = mx;
        __syncthreads();
        mx = fmaxf(fmaxf(rmax[0],rmax[1]), fmaxf(rmax[2],rmax[3]));

        const float e0 = __expf(v0-mx), e1 = __expf(v1-mx);
        float s = e0+e1;
        #pragma unroll
        for (int off=32; off>0; off>>=1) s += __shfl_down(s, off, 64);
        if (ln==0) rsum[wv] = s;
        __syncthreads();
        const float inv = 1.0f/(rsum[0]+rsum[1]+rsum[2]+rsum[3]);

        const size_t orow = (((size_t)c*KC + k)*NP + n)*NP;
        float a0 = cheb[krow+tid]    *e0*inv;
        float a1 = cheb[krow+tid+256]*e1*inv;
        unsigned short h0 = f2bf(a0), h1 = f2bf(a1);
        unsigned short l0 = f2bf(a0 - bf2f(h0)), l1 = f2bf(a1 - bf2f(h1));
        Ah[orow+tid]     = h0;  Al[orow+tid]     = l0;
        Ah[orow+tid+256] = h1;  Al[orow+tid+256] = l1;
    } else {
        // ---- x-transpose path: x[b][m][col] fp32 -> Xt[c][col][m] bf16 ----
        const int t = blockIdx.x - KC*NP;      // 0..511
        const int m0 = (t & 7)*64, col0 = (t >> 3)*64;
        const float* xb = x + (size_t)b*NP*COLS;
        const int r = tid >> 4, f4 = tid & 15;
        #pragma unroll
        for (int j=0;j<4;j++) {
            float4 v = *(const float4*)&xb[(size_t)(m0 + r + j*16)*COLS + col0 + f4*4];
            *(float4*)&Ls[r + j*16][f4*4] = v;
        }
        __syncthreads();
        const int oc = tid >> 2, seg = tid & 3;   // output row (col), m-segment of 16
        unsigned short h[16];
        #pragma unroll
        for (int u=0;u<16;u++) h[u] = f2bf(Ls[seg*16 + u][oc]);
        size_t off = ((size_t)c*COLS + col0 + oc)*NP + m0 + seg*16;
        *(uint4*)&Xth[off]   = *(const uint4*)&h[0];
        *(uint4*)&Xth[off+8] = *(const uint4*)&h[8];
    }
}

// ---------------------------------------------------------------------------
// K3: bf16x2 fused MFMA GEMM: Y[c,k,n,col] = sum_m (Ah+Al)[n,m] * Xh[m,col].
// K = 512 (m). Working set per XCD: A h+l 3.1MB + X h 4.2MB; per colg-group
// live set ~3.6MB -> L2-fits. Double-buffered LDS (2x24KB -> 3 blocks/CU),
// one barrier/chunk, LDS granule-XOR swizzle via pre-swizzled global source.
// Output Y in fp16 (nontemporal stores: halves write traffic + L2 pollution).
// ---------------------------------------------------------------------------
__global__ __launch_bounds__(256) void k_gemm(
    const unsigned short* __restrict__ Ah, const unsigned short* __restrict__ Al,
    const unsigned short* __restrict__ Xth,
    _Float16* __restrict__ Y)
{
    __shared__ __align__(16) unsigned short Ash[2][128*32];
    __shared__ __align__(16) unsigned short Asl[2][128*32];
    __shared__ __align__(16) unsigned short Bsh[2][128*32];

    const int tid  = threadIdx.x;
    const int lane = tid & 63, wave = tid >> 6;
    const int wr = wave >> 1, wc = wave & 1;
    const int lr = lane & 15, quad = lane >> 4;

    // XCD-aware mapping. grid = (384, C). For C in {8,16,32}: XCD s owns
    // c in {s, s+8, ...}, processed group-sequentially (q-outer) so each
    // XCD's live set stays one batch slice. For C<8: simple modulo.
    const int Cg   = gridDim.y;
    const int flat = blockIdx.x + 384 * blockIdx.y;
    int c, rr;
    if (Cg >= 8) {
        const int s = flat & 7, t = flat >> 3;
        rr = t % 384;
        c  = s + 8 * (t / 384);
    } else {
        c  = flat % Cg;
        rr = flat / Cg;
    }
    const int colg = rr / 48;
    const int rem  = rr % 48;
    const int kn   = rem >> 2;           // 0..11
    const int colb = colg*4 + (rem & 3);
    const int k    = kn % 3;
    const int nb   = kn / 3;
    const int n0   = nb * 128, col0 = colb * 128;

    const unsigned short* Ah_ = Ah  + ((size_t)(c*KC + k)*NP)*NP;
    const unsigned short* Al_ = Al  + ((size_t)(c*KC + k)*NP)*NP;
    const unsigned short* Bh_ = Xth + (size_t)c*COLS*NP;

    f32x4 acc[4][4];
    #pragma unroll
    for (int i=0;i<4;i++)
        #pragma unroll
        for (int j=0;j<4;j++)
            acc[i][j] = (f32x4){0.f,0.f,0.f,0.f};

    const int sr  = tid >> 2;                           // staging row 0..63
    // staged slot s holds global granule s ^ ((row>>1)&3); (tid>>3)&3 == (row>>1)&3
    const int qsw = (((tid & 3) ^ ((tid >> 3) & 3)) * 8);
    // read-side swizzle: slot = quad ^ ((row>>1)&3); (row>>1)&3 == (lr>>1)&3
    const int rq  = (quad ^ ((lr >> 1) & 3)) * 8;

    auto STAGE = [&](int bb, int m0) {
        const unsigned short* gah = Ah_ + ((size_t)(n0 + sr))*NP + m0 + qsw;
        const unsigned short* gal = Al_ + ((size_t)(n0 + sr))*NP + m0 + qsw;
        const unsigned short* gbh = Bh_ + ((size_t)(col0 + sr))*NP + m0 + qsw;
        GLDS16(gah,          &Ash[bb][tid*8]);
        GLDS16(gah + 64*NP,  &Ash[bb][2048 + tid*8]);
        GLDS16(gal,          &Asl[bb][tid*8]);
        GLDS16(gal + 64*NP,  &Asl[bb][2048 + tid*8]);
        GLDS16(gbh,          &Bsh[bb][tid*8]);
        GLDS16(gbh + 64*NP,  &Bsh[bb][2048 + tid*8]);
    };

    STAGE(0, 0);
    int bb = 0;

    #pragma unroll 1
    for (int t = 0; t < NP/32; ++t) {
        __syncthreads();                            // buf bb ready; prev reads done
        if (t+1 < NP/32) STAGE(bb^1, 32*(t+1));     // lands under compute

        short8 ah[4], al[4], bh[4];
        #pragma unroll
        for (int i=0;i<4;i++) {
            const int ra = (wr*64 + i*16 + lr)*32 + rq;
            ah[i] = *(const short8*)&Ash[bb][ra];
            al[i] = *(const short8*)&Asl[bb][ra];
        }
        #pragma unroll
        for (int j=0;j<4;j++) {
            const int rb = (wc*64 + j*16 + lr)*32 + rq;
            bh[j] = *(const short8*)&Bsh[bb][rb];
        }
        #pragma unroll
        for (int i=0;i<4;i++)
            #pragma unroll
            for (int j=0;j<4;j++) {
                acc[i][j] = __builtin_amdgcn_mfma_f32_16x16x32_bf16(
                    ah[i], bh[j], acc[i][j], 0, 0, 0);
                acc[i][j] = __builtin_amdgcn_mfma_f32_16x16x32_bf16(
                    al[i], bh[j], acc[i][j], 0, 0, 0);
            }
        bb ^= 1;
    }

    _Float16* Yc = Y + ((size_t)(c*KC + k)*NP + n0 + wr*64)*COLS + col0 + wc*64;
    #pragma unroll
    for (int i=0;i<4;i++) {
        #pragma unroll
        for (int r=0;r<4;r++) {
            const size_t row_off = (size_t)(i*16 + quad*4 + r)*COLS;
            #pragma unroll
            for (int j=0;j<4;j++) {
                _Float16 hv = (_Float16)acc[i][j][r];
                __builtin_nontemporal_store(
                    __builtin_bit_cast(unsigned short, hv),
                    (unsigned short*)&Yc[row_off + j*16 + lr]);
            }
        }
    }
}

// ---------------------------------------------------------------------------
// K4: out[b,n,o,t] = relu( sum_{k,i} Y[c,k,n,i*64+t] * Theta[k,i,o] ).
// Y fp16 staged->fp32 in LDS (48KB); Theta fp32 from L2. 2.6e10 FLOP total.
// ---------------------------------------------------------------------------
__global__ __launch_bounds__(256) void k_theta(
    const _Float16* __restrict__ Y, const float* __restrict__ Theta,
    float* __restrict__ out, int b0)
{
    __shared__ __align__(16) float Ys[KC*FIN*TP];   // 12288 floats, 48 KB
    const int n = blockIdx.x, c = blockIdx.y;
    const int tid = threadIdx.x;

    #pragma unroll
    for (int j=0;j<6;j++) {
        int idx8 = (tid + j*256)*8;   // 0..12287 step 8
        int kk   = idx8 >> 12;
        int off  = idx8 & 4095;
        union { uint4 u; _Float16 h[8]; } v;
        v.u = *(const uint4*)&Y[((size_t)(c*KC + kk)*NP + n)*COLS + off];
        float4 lo = make_float4((float)v.h[0], (float)v.h[1], (float)v.h[2], (float)v.h[3]);
        float4 hi = make_float4((float)v.h[4], (float)v.h[5], (float)v.h[6], (float)v.h[7]);
        *(float4*)&Ys[idx8]     = lo;
        *(float4*)&Ys[idx8 + 4] = hi;
    }
    __syncthreads();

    const int o = tid & 63, tw = tid >> 6;
    float4 a0 = {0,0,0,0}, a1 = a0, a2 = a0, a3 = a0;

    #pragma unroll 8
    for (int ki = 0; ki < KC*FIN; ++ki) {
        float th = Theta[ki*FOUT + o];
        const float* ys = &Ys[ki*TP + tw*16];
        float4 y0 = *(const float4*)&ys[0];
        float4 y1 = *(const float4*)&ys[4];
        float4 y2 = *(const float4*)&ys[8];
        float4 y3 = *(const float4*)&ys[12];
        a0.x += th*y0.x; a0.y += th*y0.y; a0.z += th*y0.z; a0.w += th*y0.w;
        a1.x += th*y1.x; a1.y += th*y1.y; a1.z += th*y1.z; a1.w += th*y1.w;
        a2.x += th*y2.x; a2.y += th*y2.y; a2.z += th*y2.z; a2.w += th*y2.w;
        a3.x += th*y3.x; a3.y += th*y3.y; a3.z += th*y3.z; a3.w += th*y3.w;
    }

    float* og = out + (((size_t)(b0 + c)*NP + n)*FOUT + o)*TP + tw*16;
    float4 r0 = make_float4(fmaxf(a0.x,0.f), fmaxf(a0.y,0.f), fmaxf(a0.z,0.f), fmaxf(a0.w,0.f));
    float4 r1 = make_float4(fmaxf(a1.x,0.f), fmaxf(a1.y,0.f), fmaxf(a1.z,0.f), fmaxf(a1.w,0.f));
    float4 r2 = make_float4(fmaxf(a2.x,0.f), fmaxf(a2.y,0.f), fmaxf(a2.z,0.f), fmaxf(a2.w,0.f));
    float4 r3 = make_float4(fmaxf(a3.x,0.f), fmaxf(a3.y,0.f), fmaxf(a3.z,0.f), fmaxf(a3.w,0.f));
    *(float4*)&og[0]  = r0;
    *(float4*)&og[4]  = r1;
    *(float4*)&og[8]  = r2;
    *(float4*)&og[12] = r3;
}

// ---------------------------------------------------------------------------
extern "C" void kernel_launch(void* const* d_in, const int* in_sizes, int n_in,
                              void* d_out, int out_size, void* d_ws, size_t ws_size,
                              hipStream_t stream)
{
    const float* x      = (const float*)d_in[0];
    const float* scores = (const float*)d_in[1];
    const float* adj    = (const float*)d_in[2];
    const float* cheb   = (const float*)d_in[3];
    const float* Theta  = (const float*)d_in[4];
    const float* mask   = (const float*)d_in[5];
    float* out = (float*)d_out;

    const size_t eA = (size_t)KC*NP*NP;     // 786432 elems per A array
    const size_t eX = (size_t)COLS*NP;      // 2097152 elems
    const size_t eY = (size_t)KC*NP*COLS;   // 6291456 elems
    const size_t perB = 2*eA*2 + eX*2 + eY*2;   // ~23.1 MB per batch

    int C = (int)(ws_size / perB);
    if (C < 1) C = 1;
    if (C > BATCH) C = BATCH;
    while (BATCH % C) C--;

    char* p = (char*)d_ws;
    unsigned short* Ah  = (unsigned short*)p;  p += (size_t)C*eA*2;
    unsigned short* Al  = (unsigned short*)p;  p += (size_t)C*eA*2;
    unsigned short* Xth = (unsigned short*)p;  p += (size_t)C*eX*2;
    _Float16*       Yw  = (_Float16*)p;

    for (int b0 = 0; b0 < BATCH; b0 += C) {
        k_prep <<<dim3(KC*NP + 512, C), 256, 0, stream>>>(scores, adj, mask, cheb, x, Ah, Al, Xth, b0);
        k_gemm <<<dim3(384, C),         256, 0, stream>>>(Ah, Al, Xth, Yw);
        k_theta<<<dim3(NP, C),          256, 0, stream>>>(Yw, Theta, out, b0);
    }
}